// Round 26
// baseline (130.808 us; speedup 1.0000x reference)
//
#include <hip/hip_runtime.h>
#include <hip/hip_bf16.h>

// Problem constants
#define B_SZ   16384
#define D_SZ   768
#define H_SZ   128
#define S_SZ   65536
#define E_SZ   7

// K layout: [0,768) h_t | [768,896) s_t | [896,1664) h_ctx | 1664..1666 sent | 1667 bias | pad->1696
// N layout: [0,256) r,z summed | [256,384) i_n | [384,512) h_n | [512,519) W_e | 519 W_s | pad->528
// ROUND 26 (= r25 with 2-step chunks): M=32/block, 512 blocks, 8 waves, compact runtime-wave
// code. 2-step chunks (8 KB panels), 3 LDS buffers, 2-ahead staging (1 DMA/thread/chunk),
// counted vmcnt(1) + raw s_barrier, NT hints. LDS 32 KB -> 4 blocks/CU -> 32 waves/CU
// (2x round 25's residency, the last unexploited lever).
#define NFR    33
#define NSTEP  53

typedef __attribute__((ext_vector_type(8))) short bf16x8;
typedef __attribute__((ext_vector_type(4))) float f32x4;
typedef __attribute__((ext_vector_type(4))) unsigned int u32x4;

#define LD4(p) (*reinterpret_cast<const float4*>(p))
#define MFMA(d, a, b) d = __builtin_amdgcn_mfma_f32_16x16x32_bf16(a, b, d, 0, 0, 0)

// async global->LDS DMA, 16B/lane (dest = wave-uniform base + lane*16); aux 2 = non-temporal
#define GLDS(gp, lp) __builtin_amdgcn_global_load_lds(                              \
        (const __attribute__((address_space(1))) unsigned int*)(gp),                \
        (__attribute__((address_space(3))) unsigned int*)(lp), 16, 0, 0)
#define GLDSN(gp, lp) __builtin_amdgcn_global_load_lds(                             \
        (const __attribute__((address_space(1))) unsigned int*)(gp),                \
        (__attribute__((address_space(3))) unsigned int*)(lp), 16, 0, 2)

// counted-vmcnt pipeline barrier: allow the newest N VMEM ops to stay in flight
#define PIPE_BAR(N) do {                                                            \
        asm volatile("s_waitcnt vmcnt(" #N ")" ::: "memory");                       \
        __builtin_amdgcn_sched_barrier(0);                                          \
        __builtin_amdgcn_s_barrier();                                               \
    } while (0)

static __device__ __forceinline__ ushort f2bf(float v) {
    unsigned u = __float_as_uint(v);
    u = (u + 0x7FFFu + ((u >> 16) & 1u)) >> 16;   // RNE (pack kernel / tail only)
    return (ushort)u;
}

static __device__ __forceinline__ unsigned pk2(float x, float y) {
    unsigned a = __float_as_uint(x) + 0x8000u;
    unsigned b = __float_as_uint(y) + 0x8000u;
    return __builtin_amdgcn_perm(b, a, 0x07060302);   // [a.hi16 | b.hi16]
}

static __device__ __forceinline__ bf16x8 cvt8(float4 a, float4 b) {
    union { unsigned u[4]; bf16x8 v; } r;
    r.u[0] = pk2(a.x, a.y); r.u[1] = pk2(a.z, a.w);
    r.u[2] = pk2(b.x, b.y); r.u[3] = pk2(b.z, b.w);
    return r.v;
}

// logical packed-weight value at (n, k)
static __device__ __forceinline__ float w2_value(int n, int k,
    const float* __restrict__ W_ih, const float* __restrict__ W_hh,
    const float* __restrict__ b_ih, const float* __restrict__ b_hh,
    const float* __restrict__ W_e,  const float* __restrict__ b_e,
    const float* __restrict__ W_s,  const float* __restrict__ b_s)
{
    float v = 0.0f;
    if (n < 256) {
        if (k < 768)                        v = W_ih[(size_t)n * 771 + k];
        else if (k < 896)                   v = W_hh[(size_t)n * 128 + (k - 768)];
        else if (k >= 1664 && k < 1667)     v = W_ih[(size_t)n * 771 + 768 + (k - 1664)];
        else if (k == 1667)                 v = b_ih[n] + b_hh[n];
    } else if (n < 384) {
        if (k < 768)                        v = W_ih[(size_t)n * 771 + k];
        else if (k >= 1664 && k < 1667)     v = W_ih[(size_t)n * 771 + 768 + (k - 1664)];
        else if (k == 1667)                 v = b_ih[n];
    } else if (n < 512) {
        int g = n - 128;
        if (k >= 768 && k < 896)            v = W_hh[(size_t)g * 128 + (k - 768)];
        else if (k == 1667)                 v = b_hh[g];
    } else if (n < 520) {
        int e = n - 512;
        const float* Wr = (e < E_SZ) ? (W_e + (size_t)e * 1667) : W_s;
        if (k < 768)                        v = Wr[k];
        else if (k < 896)                   v = Wr[771 + (k - 768)];
        else if (k < 1664)                  v = Wr[899 + (k - 896)];
        else if (k < 1667)                  v = Wr[768 + (k - 1664)];
        else if (k == 1667)                 v = (e < E_SZ) ? b_e[e] : b_s[0];
    }
    return v;
}

// ---------------- pack W2 frag-major: W2f[(nf*NSTEP + kstep)*64 + lane][8] ----------------
__global__ __launch_bounds__(256) void pack_w2f_kernel(
    const float* __restrict__ W_ih, const float* __restrict__ W_hh,
    const float* __restrict__ b_ih, const float* __restrict__ b_hh,
    const float* __restrict__ W_e,  const float* __restrict__ b_e,
    const float* __restrict__ W_s,  const float* __restrict__ b_s,
    ushort* __restrict__ W2f)
{
    int tid = blockIdx.x * 256 + threadIdx.x;
    if (tid >= NFR * NSTEP * 64) return;
    int lane  = tid & 63;
    int kstep = (tid >> 6) % NSTEP;
    int nf    = tid / (NSTEP * 64);
    int n     = nf * 16 + (lane & 15);
    int kbase = kstep * 32 + (lane >> 4) * 8;
    ushort o[8];
#pragma unroll
    for (int j = 0; j < 8; ++j)
        o[j] = f2bf(w2_value(n, kbase + j, W_ih, W_hh, b_ih, b_hh, W_e, b_e, W_s, b_s));
    *reinterpret_cast<uint4*>(W2f + (size_t)tid * 8) = *reinterpret_cast<const uint4*>(o);
}

// ---------------- winner (last-write-wins) ----------------
__global__ __launch_bounds__(256) void winner_kernel(const int* __restrict__ slot_ids,
                                                     int* __restrict__ winner)
{
    int b = blockIdx.x * 256 + threadIdx.x;
    if (b < B_SZ) atomicMax(&winner[slot_ids[b]], b);
}

static __device__ __forceinline__ bf16x8 ldB(const ushort* __restrict__ W2f, int nf, int ks, int lane) {
    return *reinterpret_cast<const bf16x8*>(W2f + ((size_t)(nf * NSTEP + ks) * 64 + lane) * 8);
}

// LDS A read: 2-step panel of [32 rows][128 B], XOR-swizzled (matches pre-swizzled DMA source)
static __device__ __forceinline__ float4 lds_rd(const char* Ab, int st, int row, int h) {
    return *reinterpret_cast<const float4*>(Ab + st * 4096 + row * 128 + ((h ^ (row & 7)) << 4));
}

// ---------------- fused kernel: compact runtime-wave code, 2-step chunk pipeline ----------------
__global__ __launch_bounds__(512, 8) void fused_kernel(
    const float* __restrict__ h_t,   const float* __restrict__ h_ctx,
    const float* __restrict__ sent,  const int* __restrict__ slot_ids,
    const float* __restrict__ memory,const ushort* __restrict__ W2f,
    const int* __restrict__ winner,
    float* __restrict__ out_emo, float* __restrict__ out_shift, float* __restrict__ out_mem)
{
    __shared__ alignas(16) char  A_st[3 * 8192];      // 24 KB: 3 bufs x 2 steps x [32 rows][128 B]
    __shared__ alignas(16) f32x4 redh[8 * 64];        // 8 KB heads partials (two-phase reuse)

    const int tid  = threadIdx.x;
    const int wave = tid >> 6;
    const int lane = tid & 63;
    const int row0 = blockIdx.x * 32;
    const int cl   = lane & 15, kg = lane >> 4;

    // runtime frag ids for this wave (shared instruction stream)
    const int fR = wave, fZ = 8 + wave, fI = 16 + wave, fH = 24 + wave;

    // staging: wave w covers step w>>2 (of 2), row-block (w&3)*8..+7; 1 DMA/thread/chunk
    const int sst   = wave >> 2;
    const int srb   = wave & 3;
    const int srow  = srb * 8 + (lane >> 3);
    const int scg   = (lane & 7) ^ (srow & 7);
    const int sslot = slot_ids[row0 + srow];

    f32x4 z4 = {0.f, 0.f, 0.f, 0.f};
    f32x4 aR0 = z4, aZ0 = z4, aI0 = z4, aH0 = z4;
    f32x4 aR1 = z4, aZ1 = z4, aI1 = z4, aH1 = z4;
    f32x4 hc0 = z4, hc1 = z4;

#define STAGE(C, BASE) do {                                                               \
        const int s_ = 2 * (C) + sst;                                                     \
        char* dst_ = (BASE) + sst * 4096 + srb * 1024;                                    \
        if (s_ < 24)      GLDSN(h_t + (size_t)(row0 + srow) * D_SZ + s_ * 32 + scg * 4, dst_);          \
        else if (s_ < 28) GLDS(memory + (size_t)sslot * H_SZ + (s_ - 24) * 32 + scg * 4, dst_);         \
        else              GLDSN(h_ctx + (size_t)(row0 + srow) * D_SZ + (s_ - 28) * 32 + scg * 4, dst_); \
    } while (0)

    // prologue: stage chunks 0,1; keep chunk 1's DMA in flight
    STAGE(0, A_st); STAGE(1, A_st + 8192);
    PIPE_BAR(1);

    int bc = 0, sb = 2;

    // ---- h_t chunks 0..11 (steps 0-23) ----
#pragma unroll 1
    for (int c = 0; c < 12; ++c) {
        const char* Ab = A_st + bc * 8192;
#pragma unroll
        for (int st = 0; st < 2; ++st) {
            const int s = c * 2 + st;
            bf16x8 B0 = ldB(W2f, fR, s, lane), B1 = ldB(W2f, fZ, s, lane), B2 = ldB(W2f, fI, s, lane);
            float4 x0 = lds_rd(Ab, st, cl, 2 * kg), x1 = lds_rd(Ab, st, cl, 2 * kg + 1);
            bf16x8 a0 = cvt8(x0, x1);
            MFMA(aR0, a0, B0); MFMA(aZ0, a0, B1); MFMA(aI0, a0, B2);
            float4 y0 = lds_rd(Ab, st, 16 + cl, 2 * kg), y1 = lds_rd(Ab, st, 16 + cl, 2 * kg + 1);
            bf16x8 a1 = cvt8(y0, y1);
            MFMA(aR1, a1, B0); MFMA(aZ1, a1, B1); MFMA(aI1, a1, B2);
            if ((s & 7) == wave) {                      // wave-uniform branch
                bf16x8 Bh = ldB(W2f, 32, s, lane);
                MFMA(hc0, a0, Bh); MFMA(hc1, a1, Bh);
            }
        }
        STAGE(c + 2, A_st + sb * 8192);
        PIPE_BAR(1);
        bc = (bc == 2) ? 0 : bc + 1;
        sb = (sb == 2) ? 0 : sb + 1;
    }

    // ---- s_t chunks 12,13 (steps 24-27) ----
#pragma unroll 1
    for (int c = 12; c < 14; ++c) {
        const char* Ab = A_st + bc * 8192;
#pragma unroll
        for (int st = 0; st < 2; ++st) {
            const int s = c * 2 + st;
            bf16x8 B0 = ldB(W2f, fR, s, lane), B1 = ldB(W2f, fZ, s, lane), B2 = ldB(W2f, fH, s, lane);
            float4 x0 = lds_rd(Ab, st, cl, 2 * kg), x1 = lds_rd(Ab, st, cl, 2 * kg + 1);
            bf16x8 a0 = cvt8(x0, x1);
            MFMA(aR0, a0, B0); MFMA(aZ0, a0, B1); MFMA(aH0, a0, B2);
            float4 y0 = lds_rd(Ab, st, 16 + cl, 2 * kg), y1 = lds_rd(Ab, st, 16 + cl, 2 * kg + 1);
            bf16x8 a1 = cvt8(y0, y1);
            MFMA(aR1, a1, B0); MFMA(aZ1, a1, B1); MFMA(aH1, a1, B2);
            if ((s & 7) == wave) {                      // waves 0-3 across these chunks
                bf16x8 Bh = ldB(W2f, 32, s, lane);
                MFMA(hc0, a0, Bh); MFMA(hc1, a1, Bh);
            }
        }
        STAGE(c + 2, A_st + sb * 8192);
        PIPE_BAR(1);
        bc = (bc == 2) ? 0 : bc + 1;
        sb = (sb == 2) ? 0 : sb + 1;
    }

    // ---- ctx chunks 14..23 (steps 28-47), heads only ----
#pragma unroll 1
    for (int c = 14; c < 24; ++c) {
        const char* Ab = A_st + bc * 8192;
#pragma unroll
        for (int st = 0; st < 2; ++st) {
            const int s = c * 2 + st;
            if ((s & 7) == wave) {
                bf16x8 Bh = ldB(W2f, 32, s, lane);
                float4 x0 = lds_rd(Ab, st, cl, 2 * kg), x1 = lds_rd(Ab, st, cl, 2 * kg + 1);
                MFMA(hc0, cvt8(x0, x1), Bh);
                float4 y0 = lds_rd(Ab, st, 16 + cl, 2 * kg), y1 = lds_rd(Ab, st, 16 + cl, 2 * kg + 1);
                MFMA(hc1, cvt8(y0, y1), Bh);
            }
        }
        STAGE(c + 2, A_st + sb * 8192);
        PIPE_BAR(1);
        bc = (bc == 2) ? 0 : bc + 1;
        sb = (sb == 2) ? 0 : sb + 1;
    }

    // ---- ctx chunk 24 (steps 48-49); then drain for the final chunk ----
    {
        const char* Ab = A_st + bc * 8192;
#pragma unroll
        for (int st = 0; st < 2; ++st) {
            const int s = 48 + st;
            if ((s & 7) == wave) {
                bf16x8 Bh = ldB(W2f, 32, s, lane);
                float4 x0 = lds_rd(Ab, st, cl, 2 * kg), x1 = lds_rd(Ab, st, cl, 2 * kg + 1);
                MFMA(hc0, cvt8(x0, x1), Bh);
                float4 y0 = lds_rd(Ab, st, 16 + cl, 2 * kg), y1 = lds_rd(Ab, st, 16 + cl, 2 * kg + 1);
                MFMA(hc1, cvt8(y0, y1), Bh);
            }
        }
        PIPE_BAR(0);
        bc = (bc == 2) ? 0 : bc + 1;
    }

    // ---- ctx chunk 25 (steps 50-51) + tail step 52 + wave-local GRU ----
    {
        const char* Ab = A_st + bc * 8192;
#pragma unroll
        for (int st = 0; st < 2; ++st) {
            const int s = 50 + st;
            if ((s & 7) == wave) {
                bf16x8 Bh = ldB(W2f, 32, s, lane);
                float4 x0 = lds_rd(Ab, st, cl, 2 * kg), x1 = lds_rd(Ab, st, cl, 2 * kg + 1);
                MFMA(hc0, cvt8(x0, x1), Bh);
                float4 y0 = lds_rd(Ab, st, 16 + cl, 2 * kg), y1 = lds_rd(Ab, st, 16 + cl, 2 * kg + 1);
                MFMA(hc1, cvt8(y0, y1), Bh);
            }
        }
        // tail (k=1664..1695): sent(3) + bias-one + zeros
        const int rA0 = row0 + cl, rA1 = rA0 + 16;
        bf16x8 a0, a1;
#pragma unroll
        for (int jj = 0; jj < 8; ++jj) {
            int kk = kg * 8 + jj;
            float v0 = 0.f, v1 = 0.f;
            if (kk < 3)       { v0 = sent[(size_t)rA0 * 3 + kk]; v1 = sent[(size_t)rA1 * 3 + kk]; }
            else if (kk == 3) { v0 = 1.f; v1 = 1.f; }
            a0[jj] = (short)f2bf(v0); a1[jj] = (short)f2bf(v1);
        }
        bf16x8 T0 = ldB(W2f, fR, 52, lane), T1 = ldB(W2f, fZ, 52, lane);
        bf16x8 T2 = ldB(W2f, fI, 52, lane), T3 = ldB(W2f, fH, 52, lane);
        MFMA(aR0, a0, T0); MFMA(aZ0, a0, T1); MFMA(aI0, a0, T2); MFMA(aH0, a0, T3);
        MFMA(aR1, a1, T0); MFMA(aZ1, a1, T1); MFMA(aI1, a1, T2); MFMA(aH1, a1, T3);
        if (wave == 4) {                                // 52 & 7 == 4
            bf16x8 Bh = ldB(W2f, 32, 52, lane);
            MFMA(hc0, a0, Bh); MFMA(hc1, a1, Bh);
        }
        // wave-local GRU + winner scatter for hidden j = 16*wave + cl
        const int j = 16 * wave + cl;
#pragma unroll
        for (int rg = 0; rg < 2; ++rg) {
            const f32x4 rv = rg ? aR1 : aR0, zv = rg ? aZ1 : aZ0;
            const f32x4 iv = rg ? aI1 : aI0, hv4 = rg ? aH1 : aH0;
#pragma unroll
            for (int rr = 0; rr < 4; ++rr) {
                const int row  = row0 + rg * 16 + kg * 4 + rr;
                const int slot = slot_ids[row];
                const bool win = (winner[slot] == row);
                float rgate = 1.0f / (1.0f + __expf(-rv[rr]));
                float zg    = 1.0f / (1.0f + __expf(-zv[rr]));
                float nn    = tanhf(iv[rr] + rgate * hv4[rr]);
                float h     = memory[(size_t)slot * H_SZ + j];   // exact f32 pre-update state
                float sn    = (1.0f - zg) * nn + zg * h;
                if (win) out_mem[(size_t)slot * H_SZ + j] = sn;
            }
        }
    }

    // epilogue winner-copy: this block owns slots [bid*128, bid*128+128); NT streaming
#pragma unroll 1
    for (int k = 0; k < 8; ++k) {
        int idx  = k * 512 + tid;                // 0..4095
        int rr   = idx >> 5;                     // slot row 0..127
        int c4   = (idx & 31) * 4;
        int slot = blockIdx.x * 128 + rr;
        if (winner[slot] < 0) {
            u32x4 v = __builtin_nontemporal_load(
                reinterpret_cast<const u32x4*>(memory + (size_t)slot * H_SZ + c4));
            __builtin_nontemporal_store(v,
                reinterpret_cast<u32x4*>(out_mem + (size_t)slot * H_SZ + c4));
        }
    }

    // heads outputs: two-phase LDS reduction over 8 waves (single 8 KB buffer)
#pragma unroll 1
    for (int rg = 0; rg < 2; ++rg) {
        __syncthreads();
        redh[wave * 64 + lane] = rg ? hc1 : hc0;
        __syncthreads();
        if (tid < 64) {
            f32x4 hv = redh[tid];
#pragma unroll
            for (int w = 1; w < 8; ++w) hv += redh[w * 64 + tid];
            const int col  = tid & 15;
            const int rowb = row0 + rg * 16 + (tid >> 4) * 4;
#pragma unroll
            for (int rr = 0; rr < 4; ++rr) {
                const int row = rowb + rr;
                if (col < E_SZ)       out_emo[(size_t)row * E_SZ + col] = hv[rr];
                else if (col == E_SZ) out_shift[row] = hv[rr];
            }
        }
    }
#undef STAGE
}

// ---------------- launch ----------------
extern "C" void kernel_launch(void* const* d_in, const int* in_sizes, int n_in,
                              void* d_out, int out_size, void* d_ws, size_t ws_size,
                              hipStream_t stream)
{
    const float* h_t     = (const float*)d_in[0];
    const float* h_ctx   = (const float*)d_in[1];
    const float* sent    = (const float*)d_in[2];
    const int*   slot_ids= (const int*)  d_in[3];
    const float* memory  = (const float*)d_in[4];
    const float* W_ih    = (const float*)d_in[5];
    const float* W_hh    = (const float*)d_in[6];
    const float* b_ih    = (const float*)d_in[7];
    const float* b_hh    = (const float*)d_in[8];
    const float* W_e     = (const float*)d_in[9];
    const float* b_e     = (const float*)d_in[10];
    const float* W_s     = (const float*)d_in[11];
    const float* b_s     = (const float*)d_in[12];

    float* out       = (float*)d_out;
    float* out_emo   = out;                                    // [B,7]
    float* out_shift = out + (size_t)B_SZ * E_SZ;              // [B]
    float* out_mem   = out + (size_t)B_SZ * E_SZ + B_SZ;       // [S,H]

    int*    winner = (int*)d_ws;                               // S ints
    ushort* W2f    = (ushort*)((char*)d_ws + (size_t)S_SZ * sizeof(int));

    hipMemsetAsync(winner, 0xFF, (size_t)S_SZ * sizeof(int), stream);   // -1

    pack_w2f_kernel<<<(NFR * NSTEP * 64 + 255) / 256, 256, 0, stream>>>(
        W_ih, W_hh, b_ih, b_hh, W_e, b_e, W_s, b_s, W2f);
    winner_kernel<<<B_SZ / 256, 256, 0, stream>>>(slot_ids, winner);
    fused_kernel<<<B_SZ / 32, 512, 0, stream>>>(
        h_t, h_ctx, sent, slot_ids, memory, W2f, winner, out_emo, out_shift, out_mem);
}

// Round 27
// 74.307 us; speedup vs baseline: 1.7604x; 1.7604x over previous
//
#include <hip/hip_runtime.h>
#include <hip/hip_bf16.h>

// Problem constants
#define B_SZ   16384
#define D_SZ   768
#define H_SZ   128
#define S_SZ   65536
#define E_SZ   7

// K layout: [0,768) h_t | [768,896) s_t | [896,1664) h_ctx | 1664..1666 sent | 1667 bias | pad->1696
// N layout: [0,256) r,z summed | [256,384) i_n | [384,512) h_n | [512,519) W_e | 519 W_s | pad->528
// FINAL (= round 25, best measured: ~67 us fused profiled): M=32/block, 512 blocks, 8 waves,
// compact runtime-wave shared-instruction-stream code (I$-resident hot loop), 4-step chunks,
// 3 LDS buffers, 2-ahead staging, counted vmcnt(2) + raw s_barrier (loads ride across
// barriers), NT cache hints (streams evict-first so the 1.8 MB weight table stays L2-resident).
#define NFR    33
#define NSTEP  53

typedef __attribute__((ext_vector_type(8))) short bf16x8;
typedef __attribute__((ext_vector_type(4))) float f32x4;
typedef __attribute__((ext_vector_type(4))) unsigned int u32x4;

#define LD4(p) (*reinterpret_cast<const float4*>(p))
#define MFMA(d, a, b) d = __builtin_amdgcn_mfma_f32_16x16x32_bf16(a, b, d, 0, 0, 0)

// async global->LDS DMA, 16B/lane (dest = wave-uniform base + lane*16); aux 2 = non-temporal
#define GLDS(gp, lp) __builtin_amdgcn_global_load_lds(                              \
        (const __attribute__((address_space(1))) unsigned int*)(gp),                \
        (__attribute__((address_space(3))) unsigned int*)(lp), 16, 0, 0)
#define GLDSN(gp, lp) __builtin_amdgcn_global_load_lds(                             \
        (const __attribute__((address_space(1))) unsigned int*)(gp),                \
        (__attribute__((address_space(3))) unsigned int*)(lp), 16, 0, 2)

// counted-vmcnt pipeline barrier: allow the newest N VMEM ops to stay in flight
#define PIPE_BAR(N) do {                                                            \
        asm volatile("s_waitcnt vmcnt(" #N ")" ::: "memory");                       \
        __builtin_amdgcn_sched_barrier(0);                                          \
        __builtin_amdgcn_s_barrier();                                               \
    } while (0)

static __device__ __forceinline__ ushort f2bf(float v) {
    unsigned u = __float_as_uint(v);
    u = (u + 0x7FFFu + ((u >> 16) & 1u)) >> 16;   // RNE (pack kernel / tail only)
    return (ushort)u;
}

static __device__ __forceinline__ unsigned pk2(float x, float y) {
    unsigned a = __float_as_uint(x) + 0x8000u;
    unsigned b = __float_as_uint(y) + 0x8000u;
    return __builtin_amdgcn_perm(b, a, 0x07060302);   // [a.hi16 | b.hi16]
}

static __device__ __forceinline__ bf16x8 cvt8(float4 a, float4 b) {
    union { unsigned u[4]; bf16x8 v; } r;
    r.u[0] = pk2(a.x, a.y); r.u[1] = pk2(a.z, a.w);
    r.u[2] = pk2(b.x, b.y); r.u[3] = pk2(b.z, b.w);
    return r.v;
}

// logical packed-weight value at (n, k)
static __device__ __forceinline__ float w2_value(int n, int k,
    const float* __restrict__ W_ih, const float* __restrict__ W_hh,
    const float* __restrict__ b_ih, const float* __restrict__ b_hh,
    const float* __restrict__ W_e,  const float* __restrict__ b_e,
    const float* __restrict__ W_s,  const float* __restrict__ b_s)
{
    float v = 0.0f;
    if (n < 256) {
        if (k < 768)                        v = W_ih[(size_t)n * 771 + k];
        else if (k < 896)                   v = W_hh[(size_t)n * 128 + (k - 768)];
        else if (k >= 1664 && k < 1667)     v = W_ih[(size_t)n * 771 + 768 + (k - 1664)];
        else if (k == 1667)                 v = b_ih[n] + b_hh[n];
    } else if (n < 384) {
        if (k < 768)                        v = W_ih[(size_t)n * 771 + k];
        else if (k >= 1664 && k < 1667)     v = W_ih[(size_t)n * 771 + 768 + (k - 1664)];
        else if (k == 1667)                 v = b_ih[n];
    } else if (n < 512) {
        int g = n - 128;
        if (k >= 768 && k < 896)            v = W_hh[(size_t)g * 128 + (k - 768)];
        else if (k == 1667)                 v = b_hh[g];
    } else if (n < 520) {
        int e = n - 512;
        const float* Wr = (e < E_SZ) ? (W_e + (size_t)e * 1667) : W_s;
        if (k < 768)                        v = Wr[k];
        else if (k < 896)                   v = Wr[771 + (k - 768)];
        else if (k < 1664)                  v = Wr[899 + (k - 896)];
        else if (k < 1667)                  v = Wr[768 + (k - 1664)];
        else if (k == 1667)                 v = (e < E_SZ) ? b_e[e] : b_s[0];
    }
    return v;
}

// ---------------- pack W2 frag-major: W2f[(nf*NSTEP + kstep)*64 + lane][8] ----------------
__global__ __launch_bounds__(256) void pack_w2f_kernel(
    const float* __restrict__ W_ih, const float* __restrict__ W_hh,
    const float* __restrict__ b_ih, const float* __restrict__ b_hh,
    const float* __restrict__ W_e,  const float* __restrict__ b_e,
    const float* __restrict__ W_s,  const float* __restrict__ b_s,
    ushort* __restrict__ W2f)
{
    int tid = blockIdx.x * 256 + threadIdx.x;
    if (tid >= NFR * NSTEP * 64) return;
    int lane  = tid & 63;
    int kstep = (tid >> 6) % NSTEP;
    int nf    = tid / (NSTEP * 64);
    int n     = nf * 16 + (lane & 15);
    int kbase = kstep * 32 + (lane >> 4) * 8;
    ushort o[8];
#pragma unroll
    for (int j = 0; j < 8; ++j)
        o[j] = f2bf(w2_value(n, kbase + j, W_ih, W_hh, b_ih, b_hh, W_e, b_e, W_s, b_s));
    *reinterpret_cast<uint4*>(W2f + (size_t)tid * 8) = *reinterpret_cast<const uint4*>(o);
}

// ---------------- winner (last-write-wins) ----------------
__global__ __launch_bounds__(256) void winner_kernel(const int* __restrict__ slot_ids,
                                                     int* __restrict__ winner)
{
    int b = blockIdx.x * 256 + threadIdx.x;
    if (b < B_SZ) atomicMax(&winner[slot_ids[b]], b);
}

static __device__ __forceinline__ bf16x8 ldB(const ushort* __restrict__ W2f, int nf, int ks, int lane) {
    return *reinterpret_cast<const bf16x8*>(W2f + ((size_t)(nf * NSTEP + ks) * 64 + lane) * 8);
}

// LDS A read: 4-step panel of [32 rows][128 B], XOR-swizzled (matches pre-swizzled DMA source)
static __device__ __forceinline__ float4 lds_rd(const char* Ab, int st, int row, int h) {
    return *reinterpret_cast<const float4*>(Ab + st * 4096 + row * 128 + ((h ^ (row & 7)) << 4));
}

// ---------------- fused kernel: compact runtime-wave code, rolled pipeline ----------------
__global__ __launch_bounds__(512, 4) void fused_kernel(
    const float* __restrict__ h_t,   const float* __restrict__ h_ctx,
    const float* __restrict__ sent,  const int* __restrict__ slot_ids,
    const float* __restrict__ memory,const ushort* __restrict__ W2f,
    const int* __restrict__ winner,
    float* __restrict__ out_emo, float* __restrict__ out_shift, float* __restrict__ out_mem)
{
    __shared__ alignas(16) char  A_st[3 * 16384];     // 48 KB: 3 bufs x 4 steps x [32 rows][128 B]
    __shared__ alignas(16) f32x4 redh[2][8 * 64];     // 16 KB heads partials

    const int tid  = threadIdx.x;
    const int wave = tid >> 6;
    const int lane = tid & 63;
    const int row0 = blockIdx.x * 32;
    const int cl   = lane & 15, kg = lane >> 4;

    // runtime frag ids for this wave (shared instruction stream)
    const int fR = wave, fZ = 8 + wave, fI = 16 + wave, fH = 24 + wave;

    // staging: wave w covers steps {w>>2, (w>>2)+2}, row-block (w&3)*8..+7
    const int sst   = wave >> 2;
    const int srb   = wave & 3;
    const int srow  = srb * 8 + (lane >> 3);
    const int scg   = (lane & 7) ^ (srow & 7);
    const int sslot = slot_ids[row0 + srow];

    f32x4 z4 = {0.f, 0.f, 0.f, 0.f};
    f32x4 aR0 = z4, aZ0 = z4, aI0 = z4, aH0 = z4;
    f32x4 aR1 = z4, aZ1 = z4, aI1 = z4, aH1 = z4;
    f32x4 hc0 = z4, hc1 = z4;

#define STAGE(C, BASE) do { _Pragma("unroll")                                             \
    for (int q = 0; q < 2; ++q) {                                                         \
        const int st_ = sst + 2 * q;                                                      \
        const int s_  = 4 * (C) + st_;                                                    \
        char* dst_ = (BASE) + st_ * 4096 + srb * 1024;                                    \
        if (s_ < 24)      GLDSN(h_t + (size_t)(row0 + srow) * D_SZ + s_ * 32 + scg * 4, dst_);          \
        else if (s_ < 28) GLDS(memory + (size_t)sslot * H_SZ + (s_ - 24) * 32 + scg * 4, dst_);         \
        else              GLDSN(h_ctx + (size_t)(row0 + srow) * D_SZ + (s_ - 28) * 32 + scg * 4, dst_); \
    } } while (0)

    // prologue: stage chunks 0,1; keep chunk 1's 2 DMAs in flight
    STAGE(0, A_st); STAGE(1, A_st + 16384);
    PIPE_BAR(2);

    int bc = 0, sb = 2;

    // ---- h_t chunks 0..5 (rolled; one shared body) ----
#pragma unroll 1
    for (int c = 0; c < 6; ++c) {
        const char* Ab = A_st + bc * 16384;
#pragma unroll
        for (int st = 0; st < 4; ++st) {
            const int s = c * 4 + st;
            bf16x8 B0 = ldB(W2f, fR, s, lane), B1 = ldB(W2f, fZ, s, lane), B2 = ldB(W2f, fI, s, lane);
            float4 x0 = lds_rd(Ab, st, cl, 2 * kg), x1 = lds_rd(Ab, st, cl, 2 * kg + 1);
            bf16x8 a0 = cvt8(x0, x1);
            MFMA(aR0, a0, B0); MFMA(aZ0, a0, B1); MFMA(aI0, a0, B2);
            float4 y0 = lds_rd(Ab, st, 16 + cl, 2 * kg), y1 = lds_rd(Ab, st, 16 + cl, 2 * kg + 1);
            bf16x8 a1 = cvt8(y0, y1);
            MFMA(aR1, a1, B0); MFMA(aZ1, a1, B1); MFMA(aI1, a1, B2);
            if ((s & 7) == wave) {                      // wave-uniform branch
                bf16x8 Bh = ldB(W2f, 32, s, lane);
                MFMA(hc0, a0, Bh); MFMA(hc1, a1, Bh);
            }
        }
        STAGE(c + 2, A_st + sb * 16384);
        PIPE_BAR(2);
        bc = (bc == 2) ? 0 : bc + 1;
        sb = (sb == 2) ? 0 : sb + 1;
    }

    // ---- s_t chunk 6 (steps 24-27) ----
    {
        const char* Ab = A_st + bc * 16384;
#pragma unroll
        for (int t = 0; t < 4; ++t) {
            const int s = 24 + t;
            bf16x8 B0 = ldB(W2f, fR, s, lane), B1 = ldB(W2f, fZ, s, lane), B2 = ldB(W2f, fH, s, lane);
            float4 x0 = lds_rd(Ab, t, cl, 2 * kg), x1 = lds_rd(Ab, t, cl, 2 * kg + 1);
            bf16x8 a0 = cvt8(x0, x1);
            MFMA(aR0, a0, B0); MFMA(aZ0, a0, B1); MFMA(aH0, a0, B2);
            float4 y0 = lds_rd(Ab, t, 16 + cl, 2 * kg), y1 = lds_rd(Ab, t, 16 + cl, 2 * kg + 1);
            bf16x8 a1 = cvt8(y0, y1);
            MFMA(aR1, a1, B0); MFMA(aZ1, a1, B1); MFMA(aH1, a1, B2);
            if (t == wave) {                            // waves 0-3 only
                bf16x8 Bh = ldB(W2f, 32, s, lane);
                MFMA(hc0, a0, Bh); MFMA(hc1, a1, Bh);
            }
        }
        STAGE(8, A_st + sb * 16384);
        PIPE_BAR(2);
        bc = (bc == 2) ? 0 : bc + 1;
        sb = (sb == 2) ? 0 : sb + 1;
    }

    // ---- ctx chunks 7..10 (rolled, heads only; wave active iff (c&1)==(wave>>2)) ----
#pragma unroll 1
    for (int c = 7; c <= 10; ++c) {
        const char* Ab = A_st + bc * 16384;
        if ((c & 1) == (wave >> 2)) {
            const int st = wave & 3;
            const int s  = c * 4 + st;
            bf16x8 Bh = ldB(W2f, 32, s, lane);
            float4 x0 = lds_rd(Ab, st, cl, 2 * kg), x1 = lds_rd(Ab, st, cl, 2 * kg + 1);
            MFMA(hc0, cvt8(x0, x1), Bh);
            float4 y0 = lds_rd(Ab, st, 16 + cl, 2 * kg), y1 = lds_rd(Ab, st, 16 + cl, 2 * kg + 1);
            MFMA(hc1, cvt8(y0, y1), Bh);
        }
        STAGE(c + 2, A_st + sb * 16384);
        PIPE_BAR(2);
        bc = (bc == 2) ? 0 : bc + 1;
        sb = (sb == 2) ? 0 : sb + 1;
    }

    // ---- ctx chunk 11 (waves 4-7); drain everything for the final chunk ----
    {
        const char* Ab = A_st + bc * 16384;
        if ((wave >> 2) == 1) {
            const int st = wave & 3;
            bf16x8 Bh = ldB(W2f, 32, 44 + st, lane);
            float4 x0 = lds_rd(Ab, st, cl, 2 * kg), x1 = lds_rd(Ab, st, cl, 2 * kg + 1);
            MFMA(hc0, cvt8(x0, x1), Bh);
            float4 y0 = lds_rd(Ab, st, 16 + cl, 2 * kg), y1 = lds_rd(Ab, st, 16 + cl, 2 * kg + 1);
            MFMA(hc1, cvt8(y0, y1), Bh);
        }
        PIPE_BAR(0);
        bc = (bc == 2) ? 0 : bc + 1;
    }

    // ---- ctx chunk 12 (waves 0-3) + tail step 52 + wave-local GRU ----
    {
        const char* Ab = A_st + bc * 16384;
        if ((wave >> 2) == 0) {
            const int st = wave & 3;
            bf16x8 Bh = ldB(W2f, 32, 48 + st, lane);
            float4 x0 = lds_rd(Ab, st, cl, 2 * kg), x1 = lds_rd(Ab, st, cl, 2 * kg + 1);
            MFMA(hc0, cvt8(x0, x1), Bh);
            float4 y0 = lds_rd(Ab, st, 16 + cl, 2 * kg), y1 = lds_rd(Ab, st, 16 + cl, 2 * kg + 1);
            MFMA(hc1, cvt8(y0, y1), Bh);
        }
        // tail (k=1664..1695): sent(3) + bias-one + zeros
        const int rA0 = row0 + cl, rA1 = rA0 + 16;
        bf16x8 a0, a1;
#pragma unroll
        for (int jj = 0; jj < 8; ++jj) {
            int kk = kg * 8 + jj;
            float v0 = 0.f, v1 = 0.f;
            if (kk < 3)       { v0 = sent[(size_t)rA0 * 3 + kk]; v1 = sent[(size_t)rA1 * 3 + kk]; }
            else if (kk == 3) { v0 = 1.f; v1 = 1.f; }
            a0[jj] = (short)f2bf(v0); a1[jj] = (short)f2bf(v1);
        }
        bf16x8 T0 = ldB(W2f, fR, 52, lane), T1 = ldB(W2f, fZ, 52, lane);
        bf16x8 T2 = ldB(W2f, fI, 52, lane), T3 = ldB(W2f, fH, 52, lane);
        MFMA(aR0, a0, T0); MFMA(aZ0, a0, T1); MFMA(aI0, a0, T2); MFMA(aH0, a0, T3);
        MFMA(aR1, a1, T0); MFMA(aZ1, a1, T1); MFMA(aI1, a1, T2); MFMA(aH1, a1, T3);
        if (wave == 4) {                                // 52 & 7 == 4
            bf16x8 Bh = ldB(W2f, 32, 52, lane);
            MFMA(hc0, a0, Bh); MFMA(hc1, a1, Bh);
        }
        // wave-local GRU + winner scatter for hidden j = 16*wave + cl
        const int j = 16 * wave + cl;
#pragma unroll
        for (int rg = 0; rg < 2; ++rg) {
            const f32x4 rv = rg ? aR1 : aR0, zv = rg ? aZ1 : aZ0;
            const f32x4 iv = rg ? aI1 : aI0, hv4 = rg ? aH1 : aH0;
#pragma unroll
            for (int rr = 0; rr < 4; ++rr) {
                const int row  = row0 + rg * 16 + kg * 4 + rr;
                const int slot = slot_ids[row];
                const bool win = (winner[slot] == row);
                float rgate = 1.0f / (1.0f + __expf(-rv[rr]));
                float zg    = 1.0f / (1.0f + __expf(-zv[rr]));
                float nn    = tanhf(iv[rr] + rgate * hv4[rr]);
                float h     = memory[(size_t)slot * H_SZ + j];   // exact f32 pre-update state
                float sn    = (1.0f - zg) * nn + zg * h;
                if (win) out_mem[(size_t)slot * H_SZ + j] = sn;
            }
        }
    }

    // epilogue winner-copy: this block owns slots [bid*128, bid*128+128); NT streaming
#pragma unroll 1
    for (int k = 0; k < 8; ++k) {
        int idx  = k * 512 + tid;                // 0..4095
        int rr   = idx >> 5;                     // slot row 0..127
        int c4   = (idx & 31) * 4;
        int slot = blockIdx.x * 128 + rr;
        if (winner[slot] < 0) {
            u32x4 v = __builtin_nontemporal_load(
                reinterpret_cast<const u32x4*>(memory + (size_t)slot * H_SZ + c4));
            __builtin_nontemporal_store(v,
                reinterpret_cast<u32x4*>(out_mem + (size_t)slot * H_SZ + c4));
        }
    }

    // heads outputs: LDS reduction over 8 waves, both rowgroups
    __syncthreads();
    redh[0][wave * 64 + lane] = hc0;
    redh[1][wave * 64 + lane] = hc1;
    __syncthreads();
    if (tid < 128) {
        const int rg = tid >> 6, l = tid & 63;
        f32x4 hv = redh[rg][l];
#pragma unroll
        for (int w = 1; w < 8; ++w) hv += redh[rg][w * 64 + l];
        const int col  = l & 15;
        const int rowb = row0 + rg * 16 + (l >> 4) * 4;
#pragma unroll
        for (int rr = 0; rr < 4; ++rr) {
            const int row = rowb + rr;
            if (col < E_SZ)       out_emo[(size_t)row * E_SZ + col] = hv[rr];
            else if (col == E_SZ) out_shift[row] = hv[rr];
        }
    }
#undef STAGE
}

// ---------------- launch ----------------
extern "C" void kernel_launch(void* const* d_in, const int* in_sizes, int n_in,
                              void* d_out, int out_size, void* d_ws, size_t ws_size,
                              hipStream_t stream)
{
    const float* h_t     = (const float*)d_in[0];
    const float* h_ctx   = (const float*)d_in[1];
    const float* sent    = (const float*)d_in[2];
    const int*   slot_ids= (const int*)  d_in[3];
    const float* memory  = (const float*)d_in[4];
    const float* W_ih    = (const float*)d_in[5];
    const float* W_hh    = (const float*)d_in[6];
    const float* b_ih    = (const float*)d_in[7];
    const float* b_hh    = (const float*)d_in[8];
    const float* W_e     = (const float*)d_in[9];
    const float* b_e     = (const float*)d_in[10];
    const float* W_s     = (const float*)d_in[11];
    const float* b_s     = (const float*)d_in[12];

    float* out       = (float*)d_out;
    float* out_emo   = out;                                    // [B,7]
    float* out_shift = out + (size_t)B_SZ * E_SZ;              // [B]
    float* out_mem   = out + (size_t)B_SZ * E_SZ + B_SZ;       // [S,H]

    int*    winner = (int*)d_ws;                               // S ints
    ushort* W2f    = (ushort*)((char*)d_ws + (size_t)S_SZ * sizeof(int));

    hipMemsetAsync(winner, 0xFF, (size_t)S_SZ * sizeof(int), stream);   // -1

    pack_w2f_kernel<<<(NFR * NSTEP * 64 + 255) / 256, 256, 0, stream>>>(
        W_ih, W_hh, b_ih, b_hh, W_e, b_e, W_s, b_s, W2f);
    winner_kernel<<<B_SZ / 256, 256, 0, stream>>>(slot_ids, winner);
    fused_kernel<<<B_SZ / 32, 512, 0, stream>>>(
        h_t, h_ctx, sent, slot_ids, memory, W2f, winner, out_emo, out_shift, out_mem);
}